// Round 8
// baseline (152.998 us; speedup 1.0000x reference)
//
#include <hip/hip_runtime.h>
#include <hip/hip_bf16.h>

typedef _Float16 f16x8 __attribute__((ext_vector_type(8)));
typedef _Float16 f16x4 __attribute__((ext_vector_type(4)));
typedef float    f32x4 __attribute__((ext_vector_type(4)));

#define PE_K (-0.07195578415606394f)   // -ln(10000)/128

// ---------------------------------------------------------------------------
// prep_k: fused {PE-add + NCHW f32 -> NHWC f16 transpose} for x and y, plus
// all 4 weight packs. blocks [0,128)=x tiles, [128,640)=y tiles, [640,928)=pack.
// ---------------------------------------------------------------------------
__global__ __launch_bounds__(256)
void prep_k(const float* __restrict__ x, const float* __restrict__ y,
            const float* __restrict__ wq1, const float* __restrict__ wq2,
            const float* __restrict__ wk1, const float* __restrict__ wk2,
            _Float16* __restrict__ xpe, _Float16* __restrict__ ype,
            _Float16* __restrict__ wp)
{
    __shared__ _Float16 sh[64 * 136];
    const int bx  = blockIdx.x;
    const int tid = threadIdx.x;

    if (bx < 640) {
        const float* src; _Float16* dst; int PIX, b, p0;
        if (bx < 128) { src = x; dst = xpe; PIX = 1024; b = bx >> 4; p0 = (bx & 15) << 6; }
        else { int t = bx - 128; src = y; dst = ype; PIX = 4096; b = t >> 6; p0 = (t & 63) << 6; }

        const int c     = tid & 127;
        const int ph    = (tid >> 7) << 5;           // 0 or 32
        const int start = p0 + ph;
        const float frow = (float)(c * (PIX >> 7) + (start >> 7));
        const int colbase = start & 127;

        const float* xr = src + ((size_t)b * 128 + c) * PIX + start;
#pragma unroll
        for (int i = 0; i < 32; i += 4) {
            float4 xv = *(const float4*)(xr + i);
            int col = colbase + i;                   // even
            float s0, c0, s1, c1;
            __sincosf(frow * __expf(PE_K * (float)col),       &s0, &c0);
            __sincosf(frow * __expf(PE_K * (float)(col + 2)), &s1, &c1);
            sh[(ph + i + 0) * 136 + c] = (_Float16)(xv.x + s0);
            sh[(ph + i + 1) * 136 + c] = (_Float16)(xv.y + c0);
            sh[(ph + i + 2) * 136 + c] = (_Float16)(xv.z + s1);
            sh[(ph + i + 3) * 136 + c] = (_Float16)(xv.w + c1);
        }
        __syncthreads();

        const int p   = tid >> 2;
        const int c0i = (tid & 3) << 5;
        _Float16* orow = dst + ((size_t)b * PIX + p0 + p) * 128 + c0i;
        uint4 v0 = *(const uint4*)&sh[p * 136 + c0i];
        uint4 v1 = *(const uint4*)&sh[p * 136 + c0i + 8];
        uint4 v2 = *(const uint4*)&sh[p * 136 + c0i + 16];
        uint4 v3 = *(const uint4*)&sh[p * 136 + c0i + 24];
        ((uint4*)orow)[0] = v0; ((uint4*)orow)[1] = v1;
        ((uint4*)orow)[2] = v2; ((uint4*)orow)[3] = v3;
    } else {
        // weight pack: OIHW f32 -> MFMA A-fragment-major f16
        int g    = bx - 640;                         // 0..287
        int widx = g / 72;                           // uniform per block
        const float* w = widx == 0 ? wq1 : widx == 1 ? wq2 : widx == 2 ? wk1 : wk2;
        _Float16*    o = wp + (size_t)widx * 147456;
        int gid = (g - widx * 72) * 256 + tid;       // 0..18431
        int f = gid >> 6, l = gid & 63;
        int t = f >> 5, cc = (f >> 3) & 3, mm = f & 7;
        int co  = mm * 16 + (l & 15);
        int ci0 = cc * 32 + (l >> 4) * 8;
        f16x8 pk;
#pragma unroll
        for (int i = 0; i < 8; ++i)
            pk[i] = (_Float16)w[(co * 128 + ci0 + i) * 9 + t];
        *(f16x8*)(o + (size_t)gid * 8) = pk;
    }
}

// ---------------------------------------------------------------------------
// implicit-GEMM 3x3 conv body, MFMA 16x16x32 f16. In: NHWC f16.
// Out: NHWC f16 +ReLU, or NCHW f16 * oscale. Wave = MTW m-tiles x NTW n-tiles.
// K-loop is cc-outer (4 ci-chunks); each cc loads ALL 9 taps' weight
// A-fragments into registers in one clustered batch (one exposed L2 latency
// per cc instead of per step); the 9-tap inner loop is pure ds_read+MFMA.
// cc=0's batch is issued before __syncthreads to hide under LDS staging.
// ---------------------------------------------------------------------------
template<int WW, int HH, int NROWS, int COSPLIT, int MTW, int NTW,
         bool RELU, bool NCHW_OUT>
__device__ __forceinline__
void conv_body(const _Float16* __restrict__ in, const _Float16* __restrict__ wp,
               const float* __restrict__ bias, void* __restrict__ outv,
               float oscale, int bx, _Float16* lds)
{
    constexpr int PIX   = WW * HH;
    constexpr int SLABS = NROWS + 2;
    constexpr int NTPR  = WW / 16;
    constexpr int LST   = 132;
    constexpr int GPB   = (HH / NROWS) * COSPLIT;
    constexpr int NGRP  = (NROWS * NTPR) / NTW;      // n-groups (waves)
    static_assert(((8 / COSPLIT) / MTW) * NGRP == 4, "wave mapping");

    const int b   = bx / GPB;
    const int r   = bx % GPB;
    const int h0  = (r / COSPLIT) * NROWS;
    const int ch  = r % COSPLIT;
    const int tid = threadIdx.x;
    const int wid = tid >> 6, lane = tid & 63;
    const int l15 = lane & 15, lg = lane >> 4;

    const int mbase = ch * (8 / COSPLIT) + (wid / NGRP) * MTW;
    const int nbase = (wid % NGRP) * NTW;

    // per-cc batched weight fragments (all compile-time indexed)
    f16x8 wf[9][MTW];
    auto ld_cc = [&](int cc) {
#pragma unroll
        for (int t = 0; t < 9; ++t)
#pragma unroll
            for (int mt = 0; mt < MTW; ++mt)
                wf[t][mt] = *(const f16x8*)(
                    wp + ((size_t)((t * 4 + cc) * 8 + mbase + mt) * 64 + lane) * 8);
    };

    ld_cc(0);   // hide the first batch under LDS staging

    const _Float16* inb = in + (size_t)b * PIX * 128;
    constexpr int CHUNKS = SLABS * WW * 16;
    for (int cid = tid; cid < CHUNKS; cid += 256) {
        int s   = cid / (WW * 16);
        int rem = cid - s * (WW * 16);
        int w   = rem >> 4;
        int c8  = (rem & 15) * 8;
        int row = h0 - 1 + s;
        uint4 v = {0u, 0u, 0u, 0u};
        if (row >= 0 && row < HH)
            v = *(const uint4*)(inb + ((size_t)row * WW + w) * 128 + c8);
        *(uint4*)&lds[(s * WW + w) * LST + c8] = v;
    }
    __syncthreads();

    f32x4 acc[MTW][NTW] = {};

#pragma unroll
    for (int cc = 0; cc < 4; ++cc) {
        if (cc > 0) ld_cc(cc);
#pragma unroll
        for (int t = 0; t < 9; ++t) {
            const int dh = t / 3, dw = t % 3;
            f16x8 bfr[NTW];
#pragma unroll
            for (int nt = 0; nt < NTW; ++nt) {
                int ntile = nbase + nt;
                int nrow  = ntile / NTPR;
                int wbase = (ntile % NTPR) * 16;
                int slab  = nrow + dh;
                int wpix  = wbase + l15 + dw - 1;
                bool ok   = (unsigned)wpix < (unsigned)WW;
                int  wc   = ok ? wpix : 0;
                uint4 rr = *(const uint4*)&lds[(slab * WW + wc) * LST + cc * 32 + lg * 8];
                if (!ok) rr = uint4{0u, 0u, 0u, 0u};
                bfr[nt] = __builtin_bit_cast(f16x8, rr);
            }
#pragma unroll
            for (int mt = 0; mt < MTW; ++mt)
#pragma unroll
                for (int nt = 0; nt < NTW; ++nt)
                    acc[mt][nt] = __builtin_amdgcn_mfma_f32_16x16x32_f16(
                        wf[t][mt], bfr[nt], acc[mt][nt], 0, 0, 0);
        }
    }

#pragma unroll
    for (int mt = 0; mt < MTW; ++mt) {
        int co = (mbase + mt) * 16 + lg * 4;
        float b0 = bias[co], b1 = bias[co + 1], b2 = bias[co + 2], b3 = bias[co + 3];
#pragma unroll
        for (int nt = 0; nt < NTW; ++nt) {
            int ntile = nbase + nt;
            int nrow  = ntile / NTPR;
            int wbase = (ntile % NTPR) * 16;
            int p     = (h0 + nrow) * WW + wbase + l15;
            float v0 = acc[mt][nt][0] + b0;
            float v1 = acc[mt][nt][1] + b1;
            float v2 = acc[mt][nt][2] + b2;
            float v3 = acc[mt][nt][3] + b3;
            if (RELU) {
                v0 = fmaxf(v0, 0.f); v1 = fmaxf(v1, 0.f);
                v2 = fmaxf(v2, 0.f); v3 = fmaxf(v3, 0.f);
            }
            if (NCHW_OUT) {
                _Float16* ob = (_Float16*)outv + ((size_t)(b * 128 + co)) * PIX + p;
                ob[0]             = (_Float16)(v0 * oscale);
                ob[(size_t)PIX]   = (_Float16)(v1 * oscale);
                ob[(size_t)2*PIX] = (_Float16)(v2 * oscale);
                ob[(size_t)3*PIX] = (_Float16)(v3 * oscale);
            } else {
                _Float16* ob = (_Float16*)outv + ((size_t)b * PIX + p) * 128 + co;
                f16x4 pk = {(_Float16)v0, (_Float16)v1, (_Float16)v2, (_Float16)v3};
                *(f16x4*)ob = pk;
            }
        }
    }
}

// ---- one layer: k-conv (blocks 0..511, long) then q-conv (512..767) -------
template<bool L1>
__global__ __launch_bounds__(256)
void conv_pair_k(const _Float16* __restrict__ qin, const _Float16* __restrict__ kin,
                 const _Float16* __restrict__ wpq, const _Float16* __restrict__ wpk,
                 const float* __restrict__ bq, const float* __restrict__ bk,
                 void* __restrict__ qout, void* __restrict__ kout, float qoscale)
{
    __shared__ _Float16 smem[3 * 64 * 132];          // 50688 B
    if (blockIdx.x < 512)
        conv_body<64, 64, 1, 1, 2, 4, L1, !L1>(kin, wpk, bk, kout, 1.f,
                                               blockIdx.x, smem);
    else
        conv_body<32, 32, 2, 2, 2, 2, L1, !L1>(qin, wpq, bq, qout, qoscale,
                                               blockIdx.x - 512, smem);
}

// ---------------------------------------------------------------------------
// MFMA flash attention, split-K 2-way (unchanged).
// ---------------------------------------------------------------------------
__global__ __launch_bounds__(512)
void attn_mfma_k(const _Float16* __restrict__ q, const _Float16* __restrict__ k,
                 const float* __restrict__ v, float* __restrict__ part)
{
    __shared__ float vs[2048];
    __shared__ float red[8][64][3];

    const int bx  = blockIdx.x;
    const int b   = bx & 7;                          // XCD-pinned batch
    const int qt  = (bx >> 3) & 15;
    const int kv  = bx >> 7;
    const int tid = threadIdx.x;
    const int wid = tid >> 6, lane = tid & 63;
    const int l15 = lane & 15, lg = lane >> 4;

    const _Float16* qb = q + ((size_t)b * 1024 + qt * 64) * 128;
    const _Float16* kb = k + ((size_t)b * 4096 + kv * 2048 + wid * 256) * 128;
    const float*    vb = v + (size_t)b * 4096 + kv * 2048;

    *(float4*)&vs[tid * 4] = *(const float4*)&vb[tid * 4];

    f16x8 qf[4][4];
#pragma unroll
    for (int qti = 0; qti < 4; ++qti)
#pragma unroll
        for (int cc = 0; cc < 4; ++cc)
            qf[qti][cc] = *(const f16x8*)(qb + (size_t)(qti * 16 + l15) * 128 + cc * 32 + lg * 8);
    __syncthreads();

    float m[4], num[4], den[4];
#pragma unroll
    for (int a = 0; a < 4; ++a) { m[a] = -1e30f; num[a] = 0.f; den[a] = 0.f; }

    f16x8 kf[2][4];
#pragma unroll
    for (int cc = 0; cc < 4; ++cc) {
        kf[0][cc] = *(const f16x8*)(kb + (size_t)(l15)      * 128 + cc * 32 + lg * 8);
        kf[1][cc] = *(const f16x8*)(kb + (size_t)(16 + l15) * 128 + cc * 32 + lg * 8);
    }

#pragma unroll
    for (int kt = 0; kt < 16; ++kt) {
        f32x4 acc[4] = {};
#pragma unroll
        for (int cc = 0; cc < 4; ++cc) {
#pragma unroll
            for (int qti = 0; qti < 4; ++qti)
                acc[qti] = __builtin_amdgcn_mfma_f32_16x16x32_f16(
                    kf[kt & 1][cc], qf[qti][cc], acc[qti], 0, 0, 0);
        }
        if (kt + 2 < 16) {
#pragma unroll
            for (int cc = 0; cc < 4; ++cc)
                kf[kt & 1][cc] = *(const f16x8*)(kb + (size_t)((kt + 2) * 16 + l15) * 128 + cc * 32 + lg * 8);
        }

        float4 vv = *(const float4*)&vs[wid * 256 + kt * 16 + lg * 4];
#pragma unroll
        for (int qti = 0; qti < 4; ++qti) {
            float s0 = acc[qti][0], s1 = acc[qti][1], s2 = acc[qti][2], s3 = acc[qti][3];
            float smax = fmaxf(fmaxf(s0, s1), fmaxf(s2, s3));
            float mn = fmaxf(m[qti], smax);
            float c0 = __expf(m[qti] - mn);
            float e0 = __expf(s0 - mn);
            float e1 = __expf(s1 - mn);
            float e2 = __expf(s2 - mn);
            float e3 = __expf(s3 - mn);
            num[qti] = num[qti] * c0 + e0 * vv.x + e1 * vv.y + e2 * vv.z + e3 * vv.w;
            den[qti] = den[qti] * c0 + ((e0 + e1) + (e2 + e3));
            m[qti]   = mn;
        }
    }

#pragma unroll
    for (int off = 16; off <= 32; off <<= 1) {
#pragma unroll
        for (int qti = 0; qti < 4; ++qti) {
            float mo = __shfl_xor(m[qti], off);
            float no = __shfl_xor(num[qti], off);
            float dd = __shfl_xor(den[qti], off);
            float mn = fmaxf(m[qti], mo);
            float c0 = __expf(m[qti] - mn);
            float c1 = __expf(mo - mn);
            num[qti] = num[qti] * c0 + no * c1;
            den[qti] = den[qti] * c0 + dd * c1;
            m[qti]   = mn;
        }
    }
    if (lg == 0) {
#pragma unroll
        for (int qti = 0; qti < 4; ++qti) {
            red[wid][qti * 16 + l15][0] = m[qti];
            red[wid][qti * 16 + l15][1] = num[qti];
            red[wid][qti * 16 + l15][2] = den[qti];
        }
    }
    __syncthreads();
    if (tid < 64) {
        float M = -1e30f, N = 0.f, D = 0.f;
#pragma unroll
        for (int w = 0; w < 8; ++w) {
            float mo = red[w][tid][0], no = red[w][tid][1], dd = red[w][tid][2];
            float mn = fmaxf(M, mo);
            float c0 = __expf(M - mn);
            float c1 = __expf(mo - mn);
            N = N * c0 + no * c1;
            D = D * c0 + dd * c1;
            M = mn;
        }
        float4 o = {M, N, D, 0.f};
        ((float4*)part)[((size_t)(b * 2 + kv)) * 1024 + qt * 64 + tid] = o;
    }
}

// ---- combine the 2 kv-half partials per q-row -----------------------------
__global__ __launch_bounds__(256)
void attn_fin_k(const float* __restrict__ part, float* __restrict__ out)
{
    int gid = blockIdx.x * 256 + threadIdx.x;        // 8192
    int b = gid >> 10, row = gid & 1023;
    const float4* p4 = (const float4*)part;
    float4 a = p4[(size_t)(b * 2 + 0) * 1024 + row];
    float4 c = p4[(size_t)(b * 2 + 1) * 1024 + row];
    float mn = fmaxf(a.x, c.x);
    float ea = __expf(a.x - mn), ec = __expf(c.x - mn);
    out[gid] = (a.y * ea + c.y * ec) / (a.z * ea + c.z * ec);
}

// ---------------------------------------------------------------------------
extern "C" void kernel_launch(void* const* d_in, const int* in_sizes, int n_in,
                              void* d_out, int out_size, void* d_ws, size_t ws_size,
                              hipStream_t stream)
{
    const float* x   = (const float*)d_in[0];
    const float* y   = (const float*)d_in[1];
    const float* z   = (const float*)d_in[2];
    const float* wq1 = (const float*)d_in[3];
    const float* bq1 = (const float*)d_in[4];
    const float* wq2 = (const float*)d_in[5];
    const float* bq2 = (const float*)d_in[6];
    const float* wk1 = (const float*)d_in[7];
    const float* bk1 = (const float*)d_in[8];
    const float* wk2 = (const float*)d_in[9];
    const float* bk2 = (const float*)d_in[10];

    char* w8 = (char*)d_ws;
    _Float16* xpe  = (_Float16*)(w8);                  // 2 MB  NHWC f16
    _Float16* ype  = (_Float16*)(w8 + (2u  << 20));    // 8 MB  NHWC f16
    _Float16* t1   = (_Float16*)(w8 + (10u << 20));    // 2 MB  NHWC f16
    _Float16* t2   = (_Float16*)(w8 + (12u << 20));    // 8 MB  NHWC f16
    _Float16* qbuf = (_Float16*)(w8 + (20u << 20));    // 2 MB  NCHW f16 (scaled)
    _Float16* kbuf = (_Float16*)(w8 + (22u << 20));    // 8 MB  NCHW f16
    _Float16* wp   = (_Float16*)(w8 + (30u << 20));    // 4 x 288 KB packs
    float*    part = (float*)   (w8 + (32u << 20));    // 256 KB partials

    const float scale = 0.08838834764831845f;          // 128^-0.5

    prep_k<<<928, 256, 0, stream>>>(x, y, wq1, wq2, wk1, wk2, xpe, ype, wp);

    conv_pair_k<true ><<<768, 256, 0, stream>>>(xpe, ype, wp, wp + 2 * 147456,
                                                bq1, bk1, t1, t2, 1.f);
    conv_pair_k<false><<<768, 256, 0, stream>>>(t1, t2, wp + 147456, wp + 3 * 147456,
                                                bq2, bk2, qbuf, kbuf, scale);

    attn_mfma_k<<<256, 512, 0, stream>>>(qbuf, kbuf, z, part);
    attn_fin_k<<<32, 256, 0, stream>>>(part, (float*)d_out);
}

// Round 9
// 78.371 us; speedup vs baseline: 1.9522x; 1.9522x over previous
//
#include <hip/hip_runtime.h>
#include <hip/hip_bf16.h>

typedef _Float16 f16x8 __attribute__((ext_vector_type(8)));
typedef _Float16 f16x4 __attribute__((ext_vector_type(4)));
typedef float    f32x4 __attribute__((ext_vector_type(4)));

#define PE_K (-0.07195578415606394f)   // -ln(10000)/128

// global -> LDS direct DMA, 16B per lane. ldst must be wave-uniform base;
// HW writes lane i at ldst + i*16.
__device__ __forceinline__ void gld_lds16(const _Float16* g, _Float16* l)
{
    __builtin_amdgcn_global_load_lds(
        (const __attribute__((address_space(1))) void*)g,
        (__attribute__((address_space(3))) void*)l, 16, 0, 0);
}

// ---------------------------------------------------------------------------
// prep_k: {PE-add + NCHW f32 -> NHWC f16 transpose} for x and y, 4 weight
// packs, plus a zeroed 16KB page (for OOB conv staging rows).
// Tile blocks are XCD-remapped so batch b lands on XCD b (matches conv/attn).
// ---------------------------------------------------------------------------
__global__ __launch_bounds__(256)
void prep_k(const float* __restrict__ x, const float* __restrict__ y,
            const float* __restrict__ wq1, const float* __restrict__ wq2,
            const float* __restrict__ wk1, const float* __restrict__ wk2,
            _Float16* __restrict__ xpe, _Float16* __restrict__ ype,
            _Float16* __restrict__ wp, _Float16* __restrict__ zp)
{
    __shared__ _Float16 sh[64 * 136];
    const int bx  = blockIdx.x;
    const int tid = threadIdx.x;

    if (bx < 640) {
        const float* src; _Float16* dst; int PIX, b, p0;
        if (bx < 128) {
            int l = (bx & 7) * 16 + (bx >> 3);          // XCD-chunked
            src = x; dst = xpe; PIX = 1024; b = l >> 4; p0 = (l & 15) << 6;
        } else {
            int t = bx - 128;
            int l = (t & 7) * 64 + (t >> 3);            // XCD-chunked
            src = y; dst = ype; PIX = 4096; b = l >> 6; p0 = (l & 63) << 6;
        }

        const int c     = tid & 127;
        const int ph    = (tid >> 7) << 5;              // 0 or 32
        const int start = p0 + ph;
        const float frow = (float)(c * (PIX >> 7) + (start >> 7));
        const int colbase = start & 127;

        const float* xr = src + ((size_t)b * 128 + c) * PIX + start;
#pragma unroll
        for (int i = 0; i < 32; i += 4) {
            float4 xv = *(const float4*)(xr + i);
            int col = colbase + i;                      // even
            float s0, c0, s1, c1;
            __sincosf(frow * __expf(PE_K * (float)col),       &s0, &c0);
            __sincosf(frow * __expf(PE_K * (float)(col + 2)), &s1, &c1);
            sh[(ph + i + 0) * 136 + c] = (_Float16)(xv.x + s0);
            sh[(ph + i + 1) * 136 + c] = (_Float16)(xv.y + c0);
            sh[(ph + i + 2) * 136 + c] = (_Float16)(xv.z + s1);
            sh[(ph + i + 3) * 136 + c] = (_Float16)(xv.w + c1);
        }
        __syncthreads();

        const int p   = tid >> 2;
        const int c0i = (tid & 3) << 5;
        _Float16* orow = dst + ((size_t)b * PIX + p0 + p) * 128 + c0i;
        uint4 v0 = *(const uint4*)&sh[p * 136 + c0i];
        uint4 v1 = *(const uint4*)&sh[p * 136 + c0i + 8];
        uint4 v2 = *(const uint4*)&sh[p * 136 + c0i + 16];
        uint4 v3 = *(const uint4*)&sh[p * 136 + c0i + 24];
        ((uint4*)orow)[0] = v0; ((uint4*)orow)[1] = v1;
        ((uint4*)orow)[2] = v2; ((uint4*)orow)[3] = v3;
    } else if (bx < 928) {
        // weight pack: OIHW f32 -> MFMA A-fragment-major f16
        int g    = bx - 640;                            // 0..287
        int widx = g / 72;
        const float* w = widx == 0 ? wq1 : widx == 1 ? wq2 : widx == 2 ? wk1 : wk2;
        _Float16*    o = wp + (size_t)widx * 147456;
        int gid = (g - widx * 72) * 256 + tid;          // 0..18431
        int f = gid >> 6, l = gid & 63;
        int t = f >> 5, cc = (f >> 3) & 3, mm = f & 7;
        int co  = mm * 16 + (l & 15);
        int ci0 = cc * 32 + (l >> 4) * 8;
        f16x8 pk;
#pragma unroll
        for (int i = 0; i < 8; ++i)
            pk[i] = (_Float16)w[(co * 128 + ci0 + i) * 9 + t];
        *(f16x8*)(o + (size_t)gid * 8) = pk;
    } else {
        // zero page: 16 KB
        uint4 z4 = {0u, 0u, 0u, 0u};
#pragma unroll
        for (int i = 0; i < 4; ++i)
            ((uint4*)zp)[i * 256 + tid] = z4;
    }
}

// ---------------------------------------------------------------------------
// implicit-GEMM 3x3 conv body, MFMA 16x16x32 f16. In: NHWC f16.
// Staging: global_load_lds dwordx4, LINEAR LDS [slab][w][128], source
// pre-swizzled chunk^(w&15); reads use the same XOR -> conflict-free b128.
// OOB rows read a zeroed global page. Wave = MTW m-tiles x NTW n-tiles.
// ---------------------------------------------------------------------------
template<int WW, int HH, int NROWS, int COSPLIT, int MTW, int NTW,
         bool RELU, bool NCHW_OUT>
__device__ __forceinline__
void conv_body(const _Float16* __restrict__ in, const _Float16* __restrict__ wp,
               const float* __restrict__ bias, void* __restrict__ outv,
               const _Float16* __restrict__ zp,
               float oscale, int bx, _Float16* lds)
{
    constexpr int PIX   = WW * HH;
    constexpr int SLABS = NROWS + 2;
    constexpr int NTPR  = WW / 16;
    constexpr int GPB   = (HH / NROWS) * COSPLIT;
    constexpr int NGRP  = (NROWS * NTPR) / NTW;
    constexpr int CPR   = WW * 16;                   // 16B chunks per slab
    constexpr int CHUNKS = SLABS * CPR;
    static_assert(((8 / COSPLIT) / MTW) * NGRP == 4, "wave mapping");
    static_assert(CHUNKS % 256 == 0, "stage loop");

    const int b   = bx / GPB;
    const int r   = bx % GPB;
    const int h0  = (r / COSPLIT) * NROWS;
    const int ch  = r % COSPLIT;
    const int tid = threadIdx.x;
    const int wid = tid >> 6, lane = tid & 63;
    const int l15 = lane & 15, lg = lane >> 4;

    // ---- stage SLABS rows via global_load_lds (linear dest, swz source) ----
    const _Float16* inb = in + (size_t)b * PIX * 128;
#pragma unroll
    for (int it = 0; it < CHUNKS / 256; ++it) {
        int cid = it * 256 + tid;
        int s   = cid / CPR;
        int rem = cid - s * CPR;
        int w   = rem >> 4;
        int cs  = rem & 15;
        int row = h0 - 1 + s;
        const _Float16* src =
            ((unsigned)row < (unsigned)HH)
            ? inb + ((size_t)row * WW + w) * 128 + ((cs ^ (w & 15)) << 3)
            : zp + ((rem & 1023) << 3);
        gld_lds16(src, lds + ((size_t)(it * 256 + (wid << 6)) << 3));
    }
    __syncthreads();

    const int mbase = ch * (8 / COSPLIT) + (wid / NGRP) * MTW;
    const int nbase = (wid % NGRP) * NTW;

    f32x4 acc[MTW][NTW] = {};

#pragma unroll
    for (int cc = 0; cc < 4; ++cc) {
#pragma unroll
        for (int t = 0; t < 9; ++t) {
            const int dh = t / 3, dw = t % 3;
            f16x8 af[MTW];
#pragma unroll
            for (int mt = 0; mt < MTW; ++mt) {
                int f = (t * 4 + cc) * 8 + (mbase + mt);
                af[mt] = *(const f16x8*)(wp + ((size_t)f * 64 + lane) * 8);
            }
            f16x8 bfr[NTW];
#pragma unroll
            for (int nt = 0; nt < NTW; ++nt) {
                int ntile = nbase + nt;
                int nrow  = ntile / NTPR;
                int wbase = (ntile % NTPR) * 16;
                int slab  = nrow + dh;
                int wpix  = wbase + l15 + dw - 1;
                bool ok   = (unsigned)wpix < (unsigned)WW;
                int  wc   = ok ? wpix : 0;
                int  slot = (cc * 4 + lg) ^ (wc & 15);   // XOR-swizzled chunk
                uint4 rr = *(const uint4*)&lds[((size_t)(slab * WW + wc) << 7)
                                               + (slot << 3)];
                if (!ok) rr = uint4{0u, 0u, 0u, 0u};
                bfr[nt] = __builtin_bit_cast(f16x8, rr);
            }
#pragma unroll
            for (int mt = 0; mt < MTW; ++mt)
#pragma unroll
                for (int nt = 0; nt < NTW; ++nt)
                    acc[mt][nt] = __builtin_amdgcn_mfma_f32_16x16x32_f16(
                        af[mt], bfr[nt], acc[mt][nt], 0, 0, 0);
        }
    }

    // ---- epilogue ----
#pragma unroll
    for (int mt = 0; mt < MTW; ++mt) {
        int co = (mbase + mt) * 16 + lg * 4;
        float b0 = bias[co], b1 = bias[co + 1], b2 = bias[co + 2], b3 = bias[co + 3];
#pragma unroll
        for (int nt = 0; nt < NTW; ++nt) {
            int ntile = nbase + nt;
            int nrow  = ntile / NTPR;
            int wbase = (ntile % NTPR) * 16;
            int p     = (h0 + nrow) * WW + wbase + l15;
            float v0 = acc[mt][nt][0] + b0;
            float v1 = acc[mt][nt][1] + b1;
            float v2 = acc[mt][nt][2] + b2;
            float v3 = acc[mt][nt][3] + b3;
            if (RELU) {
                v0 = fmaxf(v0, 0.f); v1 = fmaxf(v1, 0.f);
                v2 = fmaxf(v2, 0.f); v3 = fmaxf(v3, 0.f);
            }
            if (NCHW_OUT) {
                _Float16* ob = (_Float16*)outv + ((size_t)(b * 128 + co)) * PIX + p;
                ob[0]             = (_Float16)(v0 * oscale);
                ob[(size_t)PIX]   = (_Float16)(v1 * oscale);
                ob[(size_t)2*PIX] = (_Float16)(v2 * oscale);
                ob[(size_t)3*PIX] = (_Float16)(v3 * oscale);
            } else {
                _Float16* ob = (_Float16*)outv + ((size_t)b * PIX + p) * 128 + co;
                f16x4 pk = {(_Float16)v0, (_Float16)v1, (_Float16)v2, (_Float16)v3};
                *(f16x4*)ob = pk;
            }
        }
    }
}

// ---- one layer: k-conv (0..255) + q-conv (256..511), XCD-chunked ----------
// logical = (bid%8)*32 + bid/8  ->  batch b entirely on XCD b, both layers
// (and attn's b=bx&7) aligned so intermediates are same-XCD L2 hits.
template<bool L1>
__global__ __launch_bounds__(256)
void conv_pair_k(const _Float16* __restrict__ qin, const _Float16* __restrict__ kin,
                 const _Float16* __restrict__ wpq, const _Float16* __restrict__ wpk,
                 const float* __restrict__ bq, const float* __restrict__ bk,
                 void* __restrict__ qout, void* __restrict__ kout,
                 const _Float16* __restrict__ zp, float qoscale)
{
    __shared__ _Float16 smem[4 * 64 * 128];          // 64 KB, linear
    const int bid = blockIdx.x;
    if (bid < 256) {
        int l = (bid & 7) * 32 + (bid >> 3);
        conv_body<64, 64, 2, 1, 4, 4, L1, !L1>(kin, wpk, bk, kout, zp, 1.f, l, smem);
    } else {
        int t = bid - 256;
        int l = (t & 7) * 32 + (t >> 3);
        conv_body<32, 32, 2, 2, 2, 2, L1, !L1>(qin, wpq, bq, qout, zp, qoscale, l, smem);
    }
}

// ---------------------------------------------------------------------------
// MFMA flash attention, split-K 2-way (unchanged).
// ---------------------------------------------------------------------------
__global__ __launch_bounds__(512)
void attn_mfma_k(const _Float16* __restrict__ q, const _Float16* __restrict__ k,
                 const float* __restrict__ v, float* __restrict__ part)
{
    __shared__ float vs[2048];
    __shared__ float red[8][64][3];

    const int bx  = blockIdx.x;
    const int b   = bx & 7;                          // XCD-pinned batch
    const int qt  = (bx >> 3) & 15;
    const int kv  = bx >> 7;
    const int tid = threadIdx.x;
    const int wid = tid >> 6, lane = tid & 63;
    const int l15 = lane & 15, lg = lane >> 4;

    const _Float16* qb = q + ((size_t)b * 1024 + qt * 64) * 128;
    const _Float16* kb = k + ((size_t)b * 4096 + kv * 2048 + wid * 256) * 128;
    const float*    vb = v + (size_t)b * 4096 + kv * 2048;

    *(float4*)&vs[tid * 4] = *(const float4*)&vb[tid * 4];

    f16x8 qf[4][4];
#pragma unroll
    for (int qti = 0; qti < 4; ++qti)
#pragma unroll
        for (int cc = 0; cc < 4; ++cc)
            qf[qti][cc] = *(const f16x8*)(qb + (size_t)(qti * 16 + l15) * 128 + cc * 32 + lg * 8);
    __syncthreads();

    float m[4], num[4], den[4];
#pragma unroll
    for (int a = 0; a < 4; ++a) { m[a] = -1e30f; num[a] = 0.f; den[a] = 0.f; }

    f16x8 kf[2][4];
#pragma unroll
    for (int cc = 0; cc < 4; ++cc) {
        kf[0][cc] = *(const f16x8*)(kb + (size_t)(l15)      * 128 + cc * 32 + lg * 8);
        kf[1][cc] = *(const f16x8*)(kb + (size_t)(16 + l15) * 128 + cc * 32 + lg * 8);
    }

#pragma unroll
    for (int kt = 0; kt < 16; ++kt) {
        f32x4 acc[4] = {};
#pragma unroll
        for (int cc = 0; cc < 4; ++cc) {
#pragma unroll
            for (int qti = 0; qti < 4; ++qti)
                acc[qti] = __builtin_amdgcn_mfma_f32_16x16x32_f16(
                    kf[kt & 1][cc], qf[qti][cc], acc[qti], 0, 0, 0);
        }
        if (kt + 2 < 16) {
#pragma unroll
            for (int cc = 0; cc < 4; ++cc)
                kf[kt & 1][cc] = *(const f16x8*)(kb + (size_t)((kt + 2) * 16 + l15) * 128 + cc * 32 + lg * 8);
        }

        float4 vv = *(const float4*)&vs[wid * 256 + kt * 16 + lg * 4];
#pragma unroll
        for (int qti = 0; qti < 4; ++qti) {
            float s0 = acc[qti][0], s1 = acc[qti][1], s2 = acc[qti][2], s3 = acc[qti][3];
            float smax = fmaxf(fmaxf(s0, s1), fmaxf(s2, s3));
            float mn = fmaxf(m[qti], smax);
            float c0 = __expf(m[qti] - mn);
            float e0 = __expf(s0 - mn);
            float e1 = __expf(s1 - mn);
            float e2 = __expf(s2 - mn);
            float e3 = __expf(s3 - mn);
            num[qti] = num[qti] * c0 + e0 * vv.x + e1 * vv.y + e2 * vv.z + e3 * vv.w;
            den[qti] = den[qti] * c0 + ((e0 + e1) + (e2 + e3));
            m[qti]   = mn;
        }
    }

#pragma unroll
    for (int off = 16; off <= 32; off <<= 1) {
#pragma unroll
        for (int qti = 0; qti < 4; ++qti) {
            float mo = __shfl_xor(m[qti], off);
            float no = __shfl_xor(num[qti], off);
            float dd = __shfl_xor(den[qti], off);
            float mn = fmaxf(m[qti], mo);
            float c0 = __expf(m[qti] - mn);
            float c1 = __expf(mo - mn);
            num[qti] = num[qti] * c0 + no * c1;
            den[qti] = den[qti] * c0 + dd * c1;
            m[qti]   = mn;
        }
    }
    if (lg == 0) {
#pragma unroll
        for (int qti = 0; qti < 4; ++qti) {
            red[wid][qti * 16 + l15][0] = m[qti];
            red[wid][qti * 16 + l15][1] = num[qti];
            red[wid][qti * 16 + l15][2] = den[qti];
        }
    }
    __syncthreads();
    if (tid < 64) {
        float M = -1e30f, N = 0.f, D = 0.f;
#pragma unroll
        for (int w = 0; w < 8; ++w) {
            float mo = red[w][tid][0], no = red[w][tid][1], dd = red[w][tid][2];
            float mn = fmaxf(M, mo);
            float c0 = __expf(M - mn);
            float c1 = __expf(mo - mn);
            N = N * c0 + no * c1;
            D = D * c0 + dd * c1;
            M = mn;
        }
        float4 o = {M, N, D, 0.f};
        ((float4*)part)[((size_t)(b * 2 + kv)) * 1024 + qt * 64 + tid] = o;
    }
}

// ---- combine the 2 kv-half partials per q-row -----------------------------
__global__ __launch_bounds__(256)
void attn_fin_k(const float* __restrict__ part, float* __restrict__ out)
{
    int gid = blockIdx.x * 256 + threadIdx.x;        // 8192
    int b = gid >> 10, row = gid & 1023;
    const float4* p4 = (const float4*)part;
    float4 a = p4[(size_t)(b * 2 + 0) * 1024 + row];
    float4 c = p4[(size_t)(b * 2 + 1) * 1024 + row];
    float mn = fmaxf(a.x, c.x);
    float ea = __expf(a.x - mn), ec = __expf(c.x - mn);
    out[gid] = (a.y * ea + c.y * ec) / (a.z * ea + c.z * ec);
}

// ---------------------------------------------------------------------------
extern "C" void kernel_launch(void* const* d_in, const int* in_sizes, int n_in,
                              void* d_out, int out_size, void* d_ws, size_t ws_size,
                              hipStream_t stream)
{
    const float* x   = (const float*)d_in[0];
    const float* y   = (const float*)d_in[1];
    const float* z   = (const float*)d_in[2];
    const float* wq1 = (const float*)d_in[3];
    const float* bq1 = (const float*)d_in[4];
    const float* wq2 = (const float*)d_in[5];
    const float* bq2 = (const float*)d_in[6];
    const float* wk1 = (const float*)d_in[7];
    const float* bk1 = (const float*)d_in[8];
    const float* wk2 = (const float*)d_in[9];
    const float* bk2 = (const float*)d_in[10];

    char* w8 = (char*)d_ws;
    _Float16* xpe  = (_Float16*)(w8);                  // 2 MB  NHWC f16
    _Float16* ype  = (_Float16*)(w8 + (2u  << 20));    // 8 MB  NHWC f16
    _Float16* t1   = (_Float16*)(w8 + (10u << 20));    // 2 MB  NHWC f16
    _Float16* t2   = (_Float16*)(w8 + (12u << 20));    // 8 MB  NHWC f16
    _Float16* qbuf = (_Float16*)(w8 + (20u << 20));    // 2 MB  NCHW f16 (scaled)
    _Float16* kbuf = (_Float16*)(w8 + (22u << 20));    // 8 MB  NCHW f16
    _Float16* wp   = (_Float16*)(w8 + (30u << 20));    // 4 x 288 KB packs
    float*    part = (float*)   (w8 + (32u << 20));    // 256 KB partials
    _Float16* zp   = (_Float16*)(w8 + (33u << 20));    // 16 KB zero page

    const float scale = 0.08838834764831845f;          // 128^-0.5

    prep_k<<<929, 256, 0, stream>>>(x, y, wq1, wq2, wk1, wk2, xpe, ype, wp, zp);

    conv_pair_k<true ><<<512, 256, 0, stream>>>(xpe, ype, wp, wp + 2 * 147456,
                                                bq1, bk1, t1, t2, zp, 1.f);
    conv_pair_k<false><<<512, 256, 0, stream>>>(t1, t2, wp + 147456, wp + 3 * 147456,
                                                bq2, bk2, qbuf, kbuf, zp, scale);

    attn_mfma_k<<<256, 512, 0, stream>>>(qbuf, kbuf, z, part);
    attn_fin_k<<<32, 256, 0, stream>>>(part, (float*)d_out);
}